// Round 13
// baseline (347.901 us; speedup 1.0000x reference)
//
#include <hip/hip_runtime.h>
#include <math.h>

constexpr int B_ = 2, S_ = 2048, D_ = 2048, NH_ = 16, NKV_ = 4, HD_ = 128;
constexpr int EQKV_ = (NH_ + 2 * NKV_) * HD_;   // 3072
constexpr int M_ = B_ * S_;                     // 4096
constexpr float EPS_ = 1e-6f;
constexpr float QSCALE_ = 0.08838834764831845f; // 1/sqrt(HD)

typedef __attribute__((ext_vector_type(8))) short bf16x8;
typedef __attribute__((ext_vector_type(4))) float f32x4;
typedef __attribute__((address_space(1))) unsigned int gu32;
typedef __attribute__((address_space(3))) unsigned int lu32;

__device__ inline ushort f2bf(float f) {   // RNE fp32->bf16 (finite inputs)
    unsigned u = __float_as_uint(f);
    return (ushort)((u + 0x7FFF + ((u >> 16) & 1)) >> 16);
}

// ------ merged pack: x | wqkv | wo -> bf16 in ONE launch (3 ranges) --------
constexpr int NP_X = M_ * D_ / 4;           // 2,097,152 float4
constexpr int NP_W = EQKV_ * D_ / 4;        // 1,572,864
constexpr int NP_O = D_ * NH_ * HD_ / 4;    // 1,048,576
__global__ __launch_bounds__(256) void pack_all(
    const float* __restrict__ x, const float* __restrict__ wqkv,
    const float* __restrict__ wo,
    ushort* __restrict__ xbf, ushort* __restrict__ wqkvbf,
    ushort* __restrict__ wobf)
{
    int i = blockIdx.x * 256 + threadIdx.x;
    const float4* src; ushort4* dst; int j;
    if (i < NP_X)                 { src = (const float4*)x;    dst = (ushort4*)xbf;    j = i; }
    else if (i < NP_X + NP_W)     { src = (const float4*)wqkv; dst = (ushort4*)wqkvbf; j = i - NP_X; }
    else if (i < NP_X + NP_W + NP_O) { src = (const float4*)wo; dst = (ushort4*)wobf;  j = i - NP_X - NP_W; }
    else return;
    float4 f = src[j];
    ushort4 u;
    u.x = f2bf(f.x); u.y = f2bf(f.y); u.z = f2bf(f.z); u.w = f2bf(f.w);
    dst[j] = u;
}

// ------- K4: C[m,n] = sum_k A[m,k]*W[n,k], bf16 MFMA -----------------------
// KEPT at BK=64 (v10/v12 measured-best for K4). Rule-21 both-sides XOR
// kills the [128][64] 16-way conflict; T1 XCD chunk swizzle.
__global__ __launch_bounds__(256) void gemm_nt_bf16(
    const ushort* __restrict__ A, const ushort* __restrict__ W,
    float* __restrict__ C, int M, int N, int K)
{
    __shared__ __align__(16) ushort As[128 * 64];   // 16 KB
    __shared__ __align__(16) ushort Bs[128 * 64];   // 16 KB
    const int t = threadIdx.x;
    const int wave = t >> 6, lane = t & 63;
    const int nwg = gridDim.x * gridDim.y;
    int wg = blockIdx.y * gridDim.x + blockIdx.x;
    wg = (wg & 7) * (nwg >> 3) + (wg >> 3);
    const int m0 = (wg / gridDim.x) * 128, n0 = (wg % gridDim.x) * 128;
    const int wm = (wave >> 1) * 64, wn = (wave & 1) * 64;
    const int lrow = lane & 15, lquad = lane >> 4;

    const int srow = t >> 3;
    const int sgo = ((t & 7) ^ (srow & 7)) * 8;      // u16 offset in row
    const ushort* Aa = A + (size_t)(m0 + srow) * K + sgo;
    const ushort* Wa = W + (size_t)(n0 + srow) * K + sgo;
    const int rs0 = (lquad ^ (lrow & 7)) * 8;        // ks=0 seg offset (u16)
    const int rs1 = rs0 ^ 32;                        // ks=1 (= seg idx ^4)

    f32x4 acc[4][4];
#pragma unroll
    for (int i = 0; i < 4; ++i)
#pragma unroll
        for (int j = 0; j < 4; ++j) acc[i][j] = (f32x4){0.f, 0.f, 0.f, 0.f};

    for (int k0 = 0; k0 < K; k0 += 64) {
        __syncthreads();
#pragma unroll
        for (int i = 0; i < 4; ++i) {
            const int ub = (wave * 64 + 256 * i) * 8;
            __builtin_amdgcn_global_load_lds(
                (const gu32*)(Aa + (size_t)(32 * i) * K + k0),
                (lu32*)(As + ub), 16, 0, 0);
            __builtin_amdgcn_global_load_lds(
                (const gu32*)(Wa + (size_t)(32 * i) * K + k0),
                (lu32*)(Bs + ub), 16, 0, 0);
        }
        __syncthreads();

#pragma unroll
        for (int ks = 0; ks < 2; ++ks) {
            const int so = ks ? rs1 : rs0;
            bf16x8 af[4], bf[4];
#pragma unroll
            for (int i = 0; i < 4; ++i) {
                af[i] = *(const bf16x8*)(As + (wm + i * 16 + lrow) * 64 + so);
                bf[i] = *(const bf16x8*)(Bs + (wn + i * 16 + lrow) * 64 + so);
            }
#pragma unroll
            for (int i = 0; i < 4; ++i)
#pragma unroll
                for (int j = 0; j < 4; ++j)
                    acc[i][j] = __builtin_amdgcn_mfma_f32_16x16x32_bf16(
                        af[i], bf[j], acc[i][j], 0, 0, 0);
        }
    }
#pragma unroll
    for (int i = 0; i < 4; ++i)
#pragma unroll
        for (int j = 0; j < 4; ++j) {
            float* cp = C + (size_t)(m0 + wm + i * 16 + lquad * 4) * N
                          + n0 + wn + j * 16 + lrow;
#pragma unroll
            for (int r = 0; r < 4; ++r) cp[(size_t)r * N] = acc[i][j][r];
        }
}

// --- K1 fused: qkv GEMM + RMSNorm + RoPE + scale + bf16 + V^T --------------
// v13: in-block SPLIT-K. 512 thr / 8 waves; waves 0-3 accumulate k in
// [0,1024), waves 4-7 k in [1024,2048), lockstep over 32 iterations (same
// 2-barrier structure). Halves the serial chain AND doubles waves/CU
// (staging 4x8KB overlays under the 34.8KB Lt -> LDS unchanged 35840B).
// One-time cross-group f32 reduction through LDS, then v9's fused epilogue
// (gated to waves 0-3; writeout uses all 512 lanes). XCD swizzle kept.
__global__ __launch_bounds__(512, 4) void gemm_qkv_fused(
    const ushort* __restrict__ A,   // xbf (M,K) bf16
    const ushort* __restrict__ W,   // wqkvbf (EQKV,K) bf16
    const float* __restrict__ freqs,
    const float* __restrict__ qw, const float* __restrict__ kw,
    ushort* __restrict__ qo, ushort* __restrict__ ko, ushort* __restrict__ vo,
    int K)
{
    // smem phases: [staging A0|A1|B0|B1 4x4096 u16] -> [red f32[128][65]]
    //              -> [Lt u16[128][136]]   (sequential, all overlaid)
    __shared__ __align__(16) ushort smem[17408];
    __shared__ float rsbuf[256];
    ushort* Lt = smem;
    float* red = (float*)smem;              // [128][65] f32 reduction buffer

    const int t = threadIdx.x;
    const int wave = t >> 6, lane = t & 63;
    const int grp = wave >> 2;              // k-half owner
    const int wl = wave & 3;                // wave-in-group
    const int tl = t & 255;                 // thread-in-group
    const int nwg = gridDim.x * gridDim.y;
    int wg = blockIdx.y * gridDim.x + blockIdx.x;
    wg = (wg & 7) * (nwg >> 3) + (wg >> 3);
    const int m0 = (wg / gridDim.x) * 128, n0 = (wg % gridDim.x) * 128;
    const int wm = (wl >> 1) * 64, wn = (wl & 1) * 64;
    const int half = wl & 1;                // 64-col half within the tile
    const int lrow = lane & 15, lquad = lane >> 4;
    const int head = n0 >> 7;               // block-uniform head id
    const int b = m0 >> 11, s0 = m0 & (S_ - 1);

    ushort* Ag = smem + grp * 4096;         // this group's A tile [128][32]
    ushort* Bg = smem + 8192 + grp * 4096;  // this group's W tile [128][32]
    const int kbase = grp * 1024;

    f32x4 acc[4][4];
#pragma unroll
    for (int i = 0; i < 4; ++i)
#pragma unroll
        for (int j = 0; j < 4; ++j) acc[i][j] = (f32x4){0.f, 0.f, 0.f, 0.f};

    for (int k0 = 0; k0 < 1024; k0 += 32) {
        __syncthreads();
#pragma unroll
        for (int i = 0; i < 2; ++i) {
            int chunk = tl + 256 * i;
            int row = chunk >> 2, seg = chunk & 3;
            int ubase = (wl * 64 + 256 * i) * 8;   // + lane*8 u16 by HW
            __builtin_amdgcn_global_load_lds(
                (const gu32*)(A + (size_t)(m0 + row) * K + kbase + k0 + seg * 8),
                (lu32*)(Ag + ubase), 16, 0, 0);
            __builtin_amdgcn_global_load_lds(
                (const gu32*)(W + (size_t)(n0 + row) * K + kbase + k0 + seg * 8),
                (lu32*)(Bg + ubase), 16, 0, 0);
        }
        __syncthreads();

        bf16x8 af[4], bf[4];
#pragma unroll
        for (int i = 0; i < 4; ++i) {
            af[i] = *(const bf16x8*)(Ag + (wm + i * 16 + lrow) * 32 + lquad * 8);
            bf[i] = *(const bf16x8*)(Bg + (wn + i * 16 + lrow) * 32 + lquad * 8);
        }
#pragma unroll
        for (int i = 0; i < 4; ++i)
#pragma unroll
            for (int j = 0; j < 4; ++j)
                acc[i][j] = __builtin_amdgcn_mfma_f32_16x16x32_bf16(
                    af[i], bf[j], acc[i][j], 0, 0, 0);
    }

    // ---- cross-group reduction: acc(grp0) += acc(grp1), 2 col-chunks ------
    __syncthreads();                        // K-loop LDS reads complete
#pragma unroll
    for (int c = 0; c < 2; ++c) {
        if (grp == 1 && half == c) {
#pragma unroll
            for (int i = 0; i < 4; ++i)
#pragma unroll
                for (int j = 0; j < 4; ++j)
#pragma unroll
                    for (int r = 0; r < 4; ++r)
                        red[(wm + i * 16 + lquad * 4 + r) * 65 + j * 16 + lrow]
                            = acc[i][j][r];
        }
        __syncthreads();
        if (grp == 0 && half == c) {
#pragma unroll
            for (int i = 0; i < 4; ++i)
#pragma unroll
                for (int j = 0; j < 4; ++j)
#pragma unroll
                    for (int r = 0; r < 4; ++r)
                        acc[i][j][r] +=
                            red[(wm + i * 16 + lquad * 4 + r) * 65 + j * 16 + lrow];
        }
        __syncthreads();
    }

    // ---- fused epilogue (group 0 computes; all threads write out) ---------
    float part[4][4];
    if (grp == 0 && head < NH_ + NKV_) {
#pragma unroll
        for (int i = 0; i < 4; ++i)
#pragma unroll
            for (int r = 0; r < 4; ++r) {
                float p = acc[i][0][r] * acc[i][0][r]
                        + acc[i][1][r] * acc[i][1][r]
                        + acc[i][2][r] * acc[i][2][r]
                        + acc[i][3][r] * acc[i][3][r];
#pragma unroll
                for (int off = 1; off < 16; off <<= 1) p += __shfl_xor(p, off);
                part[i][r] = p;
                if (lrow == 0)
                    rsbuf[half * 128 + wm + i * 16 + lquad * 4 + r] = p;
            }
    }
    __syncthreads();

    if (grp == 0) {
        if (head < NH_ + NKV_) {
            const float* nw = (head < NH_) ? qw : kw;
            float wv[4];
#pragma unroll
            for (int j = 0; j < 4; ++j) wv[j] = nw[wn + j * 16 + lrow];
#pragma unroll
            for (int i = 0; i < 4; ++i)
#pragma unroll
                for (int r = 0; r < 4; ++r) {
                    const int rowid = wm + i * 16 + lquad * 4 + r;
                    const int s = s0 + rowid;
                    const float total = part[i][r] + rsbuf[(half ^ 1) * 128 + rowid];
                    const float rs = rsqrtf(total * (1.0f / HD_) + EPS_);
#pragma unroll
                    for (int j = 0; j < 4; ++j) {
                        const int d = wn + j * 16 + lrow;
                        const float xn = acc[i][j][r] * rs * wv[j];
                        const float other = __shfl_xor(xn, 1);
                        const float fr = freqs[s * HD_ + (d & ~1)];
                        const float fi = freqs[s * HD_ + (d & ~1) + 1];
                        float out = (d & 1) ? fmaf(xn, fr, other * fi)
                                            : fmaf(xn, fr, -other * fi);
                        if (head < NH_) out *= QSCALE_;
                        Lt[rowid * 136 + d] = f2bf(out);
                    }
                }
        } else {                     // V: transpose into Lt[d][s_local]
#pragma unroll
            for (int i = 0; i < 4; ++i)
#pragma unroll
                for (int j = 0; j < 4; ++j)
#pragma unroll
                    for (int r = 0; r < 4; ++r)
                        Lt[(wn + j * 16 + lrow) * 136 + wm + i * 16 + lquad * 4 + r]
                            = f2bf(acc[i][j][r]);
        }
    }
    __syncthreads();

    // writeout: 512 threads, 4 iterations of 32 rows, 256 B per row-chunk
    const int g = t >> 4, lx16 = t & 15;   // g in [0,32)
    if (head < NH_) {
        ushort* dst0 = qo + ((size_t)(b * NH_ + head) * S_ + s0) * HD_;
#pragma unroll
        for (int it = 0; it < 4; ++it) {
            const int rowid = it * 32 + g;
            uint4 v = *(const uint4*)(Lt + rowid * 136 + lx16 * 8);
            *(uint4*)(dst0 + (size_t)rowid * HD_ + lx16 * 8) = v;
        }
    } else if (head < NH_ + NKV_) {
        const int kh = head - NH_;
        ushort* dst0 = ko + ((size_t)(b * NKV_ + kh) * S_ + s0) * HD_;
#pragma unroll
        for (int it = 0; it < 4; ++it) {
            const int rowid = it * 32 + g;
            uint4 v = *(const uint4*)(Lt + rowid * 136 + lx16 * 8);
            *(uint4*)(dst0 + (size_t)rowid * HD_ + lx16 * 8) = v;
        }
    } else {                         // V^T rows: d = rowid, s contiguous
        const int vh = head - (NH_ + NKV_);
        ushort* dst0 = vo + ((size_t)(b * NKV_ + vh) * HD_) * S_ + s0;
#pragma unroll
        for (int it = 0; it < 4; ++it) {
            const int rowid = it * 32 + g;
            uint4 v = *(const uint4*)(Lt + rowid * 136 + lx16 * 8);
            *(uint4*)(dst0 + (size_t)rowid * S_ + lx16 * 8) = v;
        }
    }
}

// ------------- K3: causal flash attention, bf16 MFMA ----------------------
// v7 structure (unchanged): 128-row Q-blocks, 8 waves, reg-staged prefetch,
// defer-max softmax, KV-split for qb>=5, launch_bounds (512,4).
__global__ __launch_bounds__(512, 4) void flash_attn_mfma(
    const ushort* __restrict__ Q,   // (B,NH,S,HD) bf16, pre-scaled
    const ushort* __restrict__ K,   // (B,NKV,S,HD) bf16
    const ushort* __restrict__ V,   // (B,NKV,HD,S) bf16 -- transposed
    ushort* __restrict__ Y,         // (B,S,NH*HD) bf16
    float* __restrict__ OP,         // [sp][128][128] f32 partial O
    float* __restrict__ ML)         // [sp][2][128] f32 (m, l)
{
    __shared__ __align__(16) ushort Ks[4 * 64 * 32];   // 16 KB
    __shared__ __align__(16) ushort Vs[2 * 128 * 32];  // 16 KB
    __shared__ __align__(16) ushort Ps[8 * 16 * 72];   // 18 KB (per wave)

    const int t = threadIdx.x, w = t >> 6, lane = t & 63;
    const int lx = lane & 15, quad = lane >> 4;
    const int h = blockIdx.y, b = blockIdx.z;

    // ---- work decode: heavy split halves first ----
    const int gx = blockIdx.x;
    int qb, halfsel, tk0, tk1;
    bool split;
    if (gx < 22) {
        split = true;
        qb = 15 - (gx >> 1);               // 15 .. 5
        halfsel = gx & 1;
        const int h0 = qb + 1;             // tiles per half
        tk0 = halfsel ? h0 : 0;
        tk1 = halfsel ? 2 * qb + 2 : h0;
    } else {
        split = false;
        qb = 26 - gx;                      // 4 .. 0
        halfsel = 0;
        tk0 = 0;
        tk1 = 2 * qb + 2;
    }
    const int q0 = qb * 128;
    const int kvh = h >> 2;

    // ---- staging map (8 waves share one 64x128 K tile + 128x64 V^T tile) --
    const int srow8 = lane >> 3, sseg8 = lane & 7;      // 8 rows x 8 segs
    const int fsw = (srow8 >> 1) & 3;                   // swizzle (row>>1)&3
    const int slotw = ((sseg8 & 3) ^ fsw) * 8;          // u16
    const int krow = w * 8 + srow8;                     // K row (k-pos), 0..63
    const int d0 = w * 8 + srow8;                       // V d-row, 0..63 (+64)
    ushort* kdst = Ks + (sseg8 >> 2) * 2048 + krow * 32 + slotw;  // kr1: +4096
    ushort* vdst = Vs + (sseg8 >> 2) * 4096 + d0 * 32 + slotw;    // vr1: +2048
    const ushort* ksrc = K + ((size_t)(b * NKV_ + kvh) * S_ + krow) * HD_
                           + sseg8 * 8;
    const ushort* vsrc = V + ((size_t)(b * NKV_ + kvh) * HD_ + d0) * S_
                           + sseg8 * 8;
    const int rslot = (quad ^ ((lx >> 1) & 3)) * 8;     // read slot (u16)

    const ushort* qb_ = Q + ((size_t)(b * NH_ + h) * S_ + q0) * HD_;
    bf16x8 aq[4];
#pragma unroll
    for (int ks = 0; ks < 4; ++ks)
        aq[ks] = *(const bf16x8*)(qb_ + (size_t)(w * 16 + lx) * HD_ + ks * 32 + quad * 8);

    f32x4 o[8];
#pragma unroll
    for (int j = 0; j < 8; ++j) o[j] = (f32x4){0.f, 0.f, 0.f, 0.f};
    float mrow[4] = {-INFINITY, -INFINITY, -INFINITY, -INFINITY};
    float lp[4] = {0.f, 0.f, 0.f, 0.f};

    uint4 kr0, kr1, vr0, vr1;
    {
        const size_t kf = (size_t)tk0 * 64;
        kr0 = *(const uint4*)(ksrc + kf * HD_);
        kr1 = *(const uint4*)(ksrc + kf * HD_ + 64);
        vr0 = *(const uint4*)(vsrc + kf);
        vr1 = *(const uint4*)(vsrc + (size_t)64 * S_ + kf);
    }

    for (int tk = tk0; tk < tk1; ++tk) {
        const int k0 = tk * 64;
        asm volatile("s_barrier" ::: "memory");
        *(uint4*)(kdst +    0) = kr0;
        *(uint4*)(kdst + 4096) = kr1;
        *(uint4*)(vdst +    0) = vr0;
        *(uint4*)(vdst + 2048) = vr1;
        asm volatile("s_waitcnt lgkmcnt(0)" ::: "memory");
        asm volatile("s_barrier" ::: "memory");

        if (tk + 1 < tk1) {
            const size_t kf = (size_t)(k0 + 64);
            kr0 = *(const uint4*)(ksrc + kf * HD_);
            kr1 = *(const uint4*)(ksrc + kf * HD_ + 64);
            vr0 = *(const uint4*)(vsrc + kf);
            vr1 = *(const uint4*)(vsrc + (size_t)64 * S_ + kf);
        }

        f32x4 s[4];
#pragma unroll
        for (int j = 0; j < 4; ++j) s[j] = (f32x4){0.f, 0.f, 0.f, 0.f};
        __builtin_amdgcn_s_setprio(1);
#pragma unroll
        for (int ks = 0; ks < 4; ++ks) {
#pragma unroll
            for (int j = 0; j < 4; ++j) {
                bf16x8 bk = *(const bf16x8*)(Ks + ks * 2048 + (j * 16 + lx) * 32 + rslot);
                s[j] = __builtin_amdgcn_mfma_f32_16x16x32_bf16(aq[ks], bk, s[j], 0, 0, 0);
            }
        }
        __builtin_amdgcn_s_setprio(0);

        // causal mask: wave-uniform trigger (covers diag + fully-masked tiles)
        const int qrow_base = q0 + w * 16 + quad * 4;
        if (k0 + 63 > q0 + w * 16) {
#pragma unroll
            for (int reg = 0; reg < 4; ++reg) {
                const int qrow = qrow_base + reg;
#pragma unroll
                for (int j = 0; j < 4; ++j)
                    if (k0 + lx + 16 * j > qrow) s[j][reg] = -INFINITY;
            }
        }

        float rmx[4];
        bool need = false;
#pragma unroll
        for (int reg = 0; reg < 4; ++reg) {
            rmx[reg] = fmaxf(fmaxf(s[0][reg], s[1][reg]),
                             fmaxf(s[2][reg], s[3][reg]));
            need |= (rmx[reg] > mrow[reg] + 8.0f);
        }
        if (__any(need)) {
#pragma unroll
            for (int reg = 0; reg < 4; ++reg) {
                float rm = rmx[reg];
#pragma unroll
                for (int off = 1; off < 16; off <<= 1)
                    rm = fmaxf(rm, __shfl_xor(rm, off));
                const float mn = fmaxf(mrow[reg], rm);
                const float alpha = __expf(mrow[reg] - mn);
                mrow[reg] = mn;
                lp[reg] *= alpha;
#pragma unroll
                for (int j = 0; j < 8; ++j) o[j][reg] *= alpha;
            }
        }
#pragma unroll
        for (int reg = 0; reg < 4; ++reg) {
#pragma unroll
            for (int j = 0; j < 4; ++j) {
                const float p = __expf(s[j][reg] - mrow[reg]);
                lp[reg] += p;
                Ps[w * 1152 + (quad * 4 + reg) * 72 + lx + 16 * j] = f2bf(p);
            }
        }

        bf16x8 ap[2];
#pragma unroll
        for (int ks2 = 0; ks2 < 2; ++ks2)
            ap[ks2] = *(const bf16x8*)(Ps + w * 1152 + lx * 72 + ks2 * 32 + quad * 8);
        __builtin_amdgcn_s_setprio(1);
#pragma unroll
        for (int jd = 0; jd < 8; ++jd) {
#pragma unroll
            for (int ks2 = 0; ks2 < 2; ++ks2) {
                bf16x8 bv = *(const bf16x8*)(Vs + ks2 * 4096 + (jd * 16 + lx) * 32 + rslot);
                o[jd] = __builtin_amdgcn_mfma_f32_16x16x32_bf16(ap[ks2], bv, o[jd], 0, 0, 0);
            }
        }
        __builtin_amdgcn_s_setprio(0);
    }

    // ---- epilogue ----
#pragma unroll
    for (int reg = 0; reg < 4; ++reg) {
        float l = lp[reg];
#pragma unroll
        for (int off = 1; off < 16; off <<= 1) l += __shfl_xor(l, off);
        lp[reg] = l;
    }
    if (!split) {
#pragma unroll
        for (int reg = 0; reg < 4; ++reg) {
            const float inv = 1.0f / lp[reg];
            const size_t yb = (size_t)(b * S_ + q0 + w * 16 + quad * 4 + reg) * (NH_ * HD_)
                            + h * HD_ + lx;
#pragma unroll
            for (int jd = 0; jd < 8; ++jd)
                Y[yb + jd * 16] = f2bf(o[jd][reg] * inv);
        }
    } else {
        const int sp = ((b * NH_ + h) * 11 + (qb - 5)) * 2 + halfsel;
        float* mlb = ML + (size_t)sp * 256;
#pragma unroll
        for (int reg = 0; reg < 4; ++reg) {
            const int row = w * 16 + quad * 4 + reg;   // 0..127
            if (lx == 0) {
                mlb[row] = mrow[reg];
                mlb[128 + row] = lp[reg];
            }
            float* ob = OP + ((size_t)sp * 128 + row) * 128 + lx;
#pragma unroll
            for (int jd = 0; jd < 8; ++jd)
                ob[jd * 16] = o[jd][reg];
        }
    }
}

// ------------- K3b: merge the two KV-halves of heavy q-blocks -------------
__global__ __launch_bounds__(256) void attn_combine(
    const float* __restrict__ OP, const float* __restrict__ ML,
    ushort* __restrict__ Y)
{
    const int gx = blockIdx.x, h = blockIdx.y, b = blockIdx.z;
    const int qb = 5 + gx;
    const int q0 = qb * 128;
    const int sp0 = ((b * NH_ + h) * 11 + gx) * 2;
    const float* ml0 = ML + (size_t)sp0 * 256;
    const float* ml1 = ML + (size_t)(sp0 + 1) * 256;
    const float* o0 = OP + (size_t)sp0 * 128 * 128;
    const float* o1 = OP + (size_t)(sp0 + 1) * 128 * 128;
    const int d = threadIdx.x & 127, rg = threadIdx.x >> 7;
#pragma unroll
    for (int r = rg; r < 128; r += 2) {
        const float m0 = ml0[r], l0 = ml0[128 + r];
        const float m1 = ml1[r], l1 = ml1[128 + r];
        const float m = fmaxf(m0, m1);
        const float w0 = __expf(m0 - m), w1 = __expf(m1 - m);
        const float inv = 1.0f / (l0 * w0 + l1 * w1);
        const float v = (o0[r * 128 + d] * w0 + o1[r * 128 + d] * w1) * inv;
        Y[((size_t)(b * S_ + q0 + r)) * (NH_ * HD_) + h * HD_ + d] = f2bf(v);
    }
}

extern "C" void kernel_launch(void* const* d_in, const int* in_sizes, int n_in,
                              void* d_out, int out_size, void* d_ws, size_t ws_size,
                              hipStream_t stream)
{
    const float* x     = (const float*)d_in[0];
    const float* freqs = (const float*)d_in[1];
    const float* wqkv  = (const float*)d_in[2];
    const float* wo    = (const float*)d_in[3];
    const float* qw    = (const float*)d_in[4];
    const float* kw    = (const float*)d_in[5];
    float* out = (float*)d_out;

    // ws layout v13 (== v9):
    //   [0..16.78M)       qbf   (B,NH,S,HD) bf16
    //   [16.78M..20.97M)  kbf   (B,NKV,S,HD) bf16
    //   [20.97M..25.17M)  vtb   (B,NKV,HD,S) bf16 transposed
    //   [25.17M..41.94M)  ybf   (B,S,NH*HD) bf16
    //   [41.94M..50.33M)  wobf
    //   [50.33M..100.66M) dead after K1 (wqkvbf, xbf) -> attn partials:
    //     OP: 704 sp x 128 x 128 f32 = 46.14M  @ 50331648
    //     ML: 704 sp x 256 f32      = 0.72M    @ 96468992
    char* ws = (char*)d_ws;
    ushort* qbf    = (ushort*)(ws + 0);
    ushort* kbf    = (ushort*)(ws + 16777216);
    ushort* vtb    = (ushort*)(ws + 20971520);
    ushort* ybf    = (ushort*)(ws + 25165824);
    ushort* wobf   = (ushort*)(ws + 41943040);
    ushort* wqkvbf = (ushort*)(ws + 50331648);
    ushort* xbf    = (ushort*)(ws + 83886080);
    float*  OP     = (float*)(ws + 50331648);
    float*  ML     = (float*)(ws + 96468992);

    // single pack launch: x + wqkv + wo (all independent of K1..K4)
    pack_all<<<(NP_X + NP_W + NP_O + 255) / 256, 256, 0, stream>>>(
        x, wqkv, wo, xbf, wqkvbf, wobf);
    // K1 fused: qkv GEMM (in-block split-K, 512 thr) + rmsnorm + rope + V^T
    gemm_qkv_fused<<<dim3(EQKV_ / 128, M_ / 128), 512, 0, stream>>>(
        xbf, wqkvbf, freqs, qw, kw, qbf, kbf, vtb, D_);
    // K3: 128-row Q-blocks, 8 waves; KV-split for qb>=5 -> ybf / partials
    flash_attn_mfma<<<dim3(27, NH_, B_), 512, 0, stream>>>(qbf, kbf, vtb, ybf,
                                                           OP, ML);
    // K3b: merge heavy-block halves -> ybf rows 640..2047 per (b,h)
    attn_combine<<<dim3(11, NH_, B_), 256, 0, stream>>>(OP, ML, ybf);
    // K4: out = y @ wo^T  (bf16 MFMA, BK=64)
    gemm_nt_bf16<<<dim3(D_ / 128, M_ / 128), 256, 0, stream>>>(
        ybf, wobf, out, M_, D_, NH_ * HD_);
}

// Round 14
// 334.895 us; speedup vs baseline: 1.0388x; 1.0388x over previous
//
#include <hip/hip_runtime.h>
#include <math.h>

constexpr int B_ = 2, S_ = 2048, D_ = 2048, NH_ = 16, NKV_ = 4, HD_ = 128;
constexpr int EQKV_ = (NH_ + 2 * NKV_) * HD_;   // 3072
constexpr int M_ = B_ * S_;                     // 4096
constexpr float EPS_ = 1e-6f;
constexpr float QSCALE_ = 0.08838834764831845f; // 1/sqrt(HD)

typedef __attribute__((ext_vector_type(8))) short bf16x8;
typedef __attribute__((ext_vector_type(4))) float f32x4;
typedef __attribute__((address_space(1))) unsigned int gu32;
typedef __attribute__((address_space(3))) unsigned int lu32;

__device__ inline ushort f2bf(float f) {   // RNE fp32->bf16 (finite inputs)
    unsigned u = __float_as_uint(f);
    return (ushort)((u + 0x7FFF + ((u >> 16) & 1)) >> 16);
}

// ------ merged pack: x | wqkv | wo -> bf16 in ONE launch (3 ranges) --------
constexpr int NP_X = M_ * D_ / 4;           // 2,097,152 float4
constexpr int NP_W = EQKV_ * D_ / 4;        // 1,572,864
constexpr int NP_O = D_ * NH_ * HD_ / 4;    // 1,048,576
__global__ __launch_bounds__(256) void pack_all(
    const float* __restrict__ x, const float* __restrict__ wqkv,
    const float* __restrict__ wo,
    ushort* __restrict__ xbf, ushort* __restrict__ wqkvbf,
    ushort* __restrict__ wobf)
{
    int i = blockIdx.x * 256 + threadIdx.x;
    const float4* src; ushort4* dst; int j;
    if (i < NP_X)                 { src = (const float4*)x;    dst = (ushort4*)xbf;    j = i; }
    else if (i < NP_X + NP_W)     { src = (const float4*)wqkv; dst = (ushort4*)wqkvbf; j = i - NP_X; }
    else if (i < NP_X + NP_W + NP_O) { src = (const float4*)wo; dst = (ushort4*)wobf;  j = i - NP_X - NP_W; }
    else return;
    float4 f = src[j];
    ushort4 u;
    u.x = f2bf(f.x); u.y = f2bf(f.y); u.z = f2bf(f.z); u.w = f2bf(f.w);
    dst[j] = u;
}

// ------- K4: C[m,n] = sum_k A[m,k]*W[n,k], bf16 MFMA -----------------------
// KEPT at BK=64 (measured-best for K4, v10/v12). Rule-21 both-sides XOR
// kills the [128][64] 16-way conflict; T1 XCD chunk swizzle.
__global__ __launch_bounds__(256) void gemm_nt_bf16(
    const ushort* __restrict__ A, const ushort* __restrict__ W,
    float* __restrict__ C, int M, int N, int K)
{
    __shared__ __align__(16) ushort As[128 * 64];   // 16 KB
    __shared__ __align__(16) ushort Bs[128 * 64];   // 16 KB
    const int t = threadIdx.x;
    const int wave = t >> 6, lane = t & 63;
    const int nwg = gridDim.x * gridDim.y;
    int wg = blockIdx.y * gridDim.x + blockIdx.x;
    wg = (wg & 7) * (nwg >> 3) + (wg >> 3);
    const int m0 = (wg / gridDim.x) * 128, n0 = (wg % gridDim.x) * 128;
    const int wm = (wave >> 1) * 64, wn = (wave & 1) * 64;
    const int lrow = lane & 15, lquad = lane >> 4;

    const int srow = t >> 3;
    const int sgo = ((t & 7) ^ (srow & 7)) * 8;      // u16 offset in row
    const ushort* Aa = A + (size_t)(m0 + srow) * K + sgo;
    const ushort* Wa = W + (size_t)(n0 + srow) * K + sgo;
    const int rs0 = (lquad ^ (lrow & 7)) * 8;        // ks=0 seg offset (u16)
    const int rs1 = rs0 ^ 32;                        // ks=1 (= seg idx ^4)

    f32x4 acc[4][4];
#pragma unroll
    for (int i = 0; i < 4; ++i)
#pragma unroll
        for (int j = 0; j < 4; ++j) acc[i][j] = (f32x4){0.f, 0.f, 0.f, 0.f};

    for (int k0 = 0; k0 < K; k0 += 64) {
        __syncthreads();
#pragma unroll
        for (int i = 0; i < 4; ++i) {
            const int ub = (wave * 64 + 256 * i) * 8;
            __builtin_amdgcn_global_load_lds(
                (const gu32*)(Aa + (size_t)(32 * i) * K + k0),
                (lu32*)(As + ub), 16, 0, 0);
            __builtin_amdgcn_global_load_lds(
                (const gu32*)(Wa + (size_t)(32 * i) * K + k0),
                (lu32*)(Bs + ub), 16, 0, 0);
        }
        __syncthreads();

#pragma unroll
        for (int ks = 0; ks < 2; ++ks) {
            const int so = ks ? rs1 : rs0;
            bf16x8 af[4], bf[4];
#pragma unroll
            for (int i = 0; i < 4; ++i) {
                af[i] = *(const bf16x8*)(As + (wm + i * 16 + lrow) * 64 + so);
                bf[i] = *(const bf16x8*)(Bs + (wn + i * 16 + lrow) * 64 + so);
            }
#pragma unroll
            for (int i = 0; i < 4; ++i)
#pragma unroll
                for (int j = 0; j < 4; ++j)
                    acc[i][j] = __builtin_amdgcn_mfma_f32_16x16x32_bf16(
                        af[i], bf[j], acc[i][j], 0, 0, 0);
        }
    }
#pragma unroll
    for (int i = 0; i < 4; ++i)
#pragma unroll
        for (int j = 0; j < 4; ++j) {
            float* cp = C + (size_t)(m0 + wm + i * 16 + lquad * 4) * N
                          + n0 + wn + j * 16 + lrow;
#pragma unroll
            for (int r = 0; r < 4; ++r) cp[(size_t)r * N] = acc[i][j][r];
        }
}

// --- K1 fused: qkv GEMM + RMSNorm + RoPE + scale + bf16 + V^T --------------
// v14 = v12's measured-best: BK=32, 256 threads (ledger: dbuf R8 -25us,
// BK=64 R10 -29us, split-K R13 -10us -- all structural variants regressed
// via L2-locality/register side-effects). XCD chunk swizzle kept.
__global__ __launch_bounds__(256) void gemm_qkv_fused(
    const ushort* __restrict__ A,   // xbf (M,K) bf16
    const ushort* __restrict__ W,   // wqkvbf (EQKV,K) bf16
    const float* __restrict__ freqs,
    const float* __restrict__ qw, const float* __restrict__ kw,
    ushort* __restrict__ qo, ushort* __restrict__ ko, ushort* __restrict__ vo,
    int K)
{
    __shared__ __align__(16) ushort smem[128 * 136];  // As|Bs during K-loop; Lt after
    __shared__ float rsbuf[256];
    ushort* As = smem;            // 128*32
    ushort* Bs = smem + 4096;     // 128*32
    ushort* Lt = smem;            // [128][136] u16 staging tile (post-loop)

    const int t = threadIdx.x;
    const int wave = t >> 6, lane = t & 63;
    const int nwg = gridDim.x * gridDim.y;
    int wg = blockIdx.y * gridDim.x + blockIdx.x;
    wg = (wg & 7) * (nwg >> 3) + (wg >> 3);
    const int m0 = (wg / gridDim.x) * 128, n0 = (wg % gridDim.x) * 128;
    const int wm = (wave >> 1) * 64, wn = (wave & 1) * 64;
    const int half = wave & 1;                 // which 64-col half this wave owns
    const int lrow = lane & 15, lquad = lane >> 4;
    const int head = n0 >> 7;                  // block-uniform: [0,16)q [16,20)k [20,24)v
    const int b = m0 >> 11, s0 = m0 & (S_ - 1);

    f32x4 acc[4][4];
#pragma unroll
    for (int i = 0; i < 4; ++i)
#pragma unroll
        for (int j = 0; j < 4; ++j) acc[i][j] = (f32x4){0.f, 0.f, 0.f, 0.f};

    for (int k0 = 0; k0 < K; k0 += 32) {
        __syncthreads();
#pragma unroll
        for (int i = 0; i < 2; ++i) {
            int chunk = t + 256 * i;
            int row = chunk >> 2, seg = chunk & 3;
            int ubase = (wave * 64 + 256 * i) * 8;
            __builtin_amdgcn_global_load_lds(
                (const gu32*)(A + (size_t)(m0 + row) * K + k0 + seg * 8),
                (lu32*)(As + ubase), 16, 0, 0);
            __builtin_amdgcn_global_load_lds(
                (const gu32*)(W + (size_t)(n0 + row) * K + k0 + seg * 8),
                (lu32*)(Bs + ubase), 16, 0, 0);
        }
        __syncthreads();

        bf16x8 af[4], bf[4];
#pragma unroll
        for (int i = 0; i < 4; ++i) {
            af[i] = *(const bf16x8*)(As + (wm + i * 16 + lrow) * 32 + lquad * 8);
            bf[i] = *(const bf16x8*)(Bs + (wn + i * 16 + lrow) * 32 + lquad * 8);
        }
#pragma unroll
        for (int i = 0; i < 4; ++i)
#pragma unroll
            for (int j = 0; j < 4; ++j)
                acc[i][j] = __builtin_amdgcn_mfma_f32_16x16x32_bf16(
                    af[i], bf[j], acc[i][j], 0, 0, 0);
    }
    __syncthreads();                 // K-loop LDS reads done; smem reusable as Lt

    float part[4][4];
    if (head < NH_ + NKV_) {
#pragma unroll
        for (int i = 0; i < 4; ++i)
#pragma unroll
            for (int r = 0; r < 4; ++r) {
                float p = acc[i][0][r] * acc[i][0][r]
                        + acc[i][1][r] * acc[i][1][r]
                        + acc[i][2][r] * acc[i][2][r]
                        + acc[i][3][r] * acc[i][3][r];
#pragma unroll
                for (int off = 1; off < 16; off <<= 1) p += __shfl_xor(p, off);
                part[i][r] = p;
                if (lrow == 0)
                    rsbuf[half * 128 + wm + i * 16 + lquad * 4 + r] = p;
            }
    }
    __syncthreads();

    if (head < NH_ + NKV_) {
        const float* nw = (head < NH_) ? qw : kw;
        float wv[4];
#pragma unroll
        for (int j = 0; j < 4; ++j) wv[j] = nw[wn + j * 16 + lrow];
#pragma unroll
        for (int i = 0; i < 4; ++i)
#pragma unroll
            for (int r = 0; r < 4; ++r) {
                const int rowid = wm + i * 16 + lquad * 4 + r;
                const int s = s0 + rowid;
                const float total = part[i][r] + rsbuf[(half ^ 1) * 128 + rowid];
                const float rs = rsqrtf(total * (1.0f / HD_) + EPS_);
#pragma unroll
                for (int j = 0; j < 4; ++j) {
                    const int d = wn + j * 16 + lrow;
                    const float xn = acc[i][j][r] * rs * wv[j];
                    const float other = __shfl_xor(xn, 1);
                    const float fr = freqs[s * HD_ + (d & ~1)];
                    const float fi = freqs[s * HD_ + (d & ~1) + 1];
                    float out = (d & 1) ? fmaf(xn, fr, other * fi)
                                        : fmaf(xn, fr, -other * fi);
                    if (head < NH_) out *= QSCALE_;
                    Lt[rowid * 136 + d] = f2bf(out);
                }
            }
    } else {                         // V: transpose into Lt[d][s_local]
#pragma unroll
        for (int i = 0; i < 4; ++i)
#pragma unroll
            for (int j = 0; j < 4; ++j)
#pragma unroll
                for (int r = 0; r < 4; ++r)
                    Lt[(wn + j * 16 + lrow) * 136 + wm + i * 16 + lquad * 4 + r]
                        = f2bf(acc[i][j][r]);
    }
    __syncthreads();

    const int g = t >> 4, lx16 = t & 15;
    if (head < NH_) {
        ushort* dst0 = qo + ((size_t)(b * NH_ + head) * S_ + s0) * HD_;
#pragma unroll
        for (int it = 0; it < 8; ++it) {
            const int rowid = it * 16 + g;
            uint4 v = *(const uint4*)(Lt + rowid * 136 + lx16 * 8);
            *(uint4*)(dst0 + (size_t)rowid * HD_ + lx16 * 8) = v;
        }
    } else if (head < NH_ + NKV_) {
        const int kh = head - NH_;
        ushort* dst0 = ko + ((size_t)(b * NKV_ + kh) * S_ + s0) * HD_;
#pragma unroll
        for (int it = 0; it < 8; ++it) {
            const int rowid = it * 16 + g;
            uint4 v = *(const uint4*)(Lt + rowid * 136 + lx16 * 8);
            *(uint4*)(dst0 + (size_t)rowid * HD_ + lx16 * 8) = v;
        }
    } else {                         // V^T rows: d = rowid, s contiguous
        const int vh = head - (NH_ + NKV_);
        ushort* dst0 = vo + ((size_t)(b * NKV_ + vh) * HD_) * S_ + s0;
#pragma unroll
        for (int it = 0; it < 8; ++it) {
            const int rowid = it * 16 + g;
            uint4 v = *(const uint4*)(Lt + rowid * 136 + lx16 * 8);
            *(uint4*)(dst0 + (size_t)rowid * S_ + lx16 * 8) = v;
        }
    }
}

// ------------- K3: causal flash attention, bf16 MFMA ----------------------
// v7 structure (unchanged): 128-row Q-blocks, 8 waves, reg-staged prefetch,
// defer-max softmax, KV-split for qb>=5, launch_bounds (512,4).
__global__ __launch_bounds__(512, 4) void flash_attn_mfma(
    const ushort* __restrict__ Q,   // (B,NH,S,HD) bf16, pre-scaled
    const ushort* __restrict__ K,   // (B,NKV,S,HD) bf16
    const ushort* __restrict__ V,   // (B,NKV,HD,S) bf16 -- transposed
    ushort* __restrict__ Y,         // (B,S,NH*HD) bf16
    float* __restrict__ OP,         // [sp][128][128] f32 partial O
    float* __restrict__ ML)         // [sp][2][128] f32 (m, l)
{
    __shared__ __align__(16) ushort Ks[4 * 64 * 32];   // 16 KB
    __shared__ __align__(16) ushort Vs[2 * 128 * 32];  // 16 KB
    __shared__ __align__(16) ushort Ps[8 * 16 * 72];   // 18 KB (per wave)

    const int t = threadIdx.x, w = t >> 6, lane = t & 63;
    const int lx = lane & 15, quad = lane >> 4;
    const int h = blockIdx.y, b = blockIdx.z;

    // ---- work decode: heavy split halves first ----
    const int gx = blockIdx.x;
    int qb, halfsel, tk0, tk1;
    bool split;
    if (gx < 22) {
        split = true;
        qb = 15 - (gx >> 1);               // 15 .. 5
        halfsel = gx & 1;
        const int h0 = qb + 1;             // tiles per half
        tk0 = halfsel ? h0 : 0;
        tk1 = halfsel ? 2 * qb + 2 : h0;
    } else {
        split = false;
        qb = 26 - gx;                      // 4 .. 0
        halfsel = 0;
        tk0 = 0;
        tk1 = 2 * qb + 2;
    }
    const int q0 = qb * 128;
    const int kvh = h >> 2;

    // ---- staging map (8 waves share one 64x128 K tile + 128x64 V^T tile) --
    const int srow8 = lane >> 3, sseg8 = lane & 7;      // 8 rows x 8 segs
    const int fsw = (srow8 >> 1) & 3;                   // swizzle (row>>1)&3
    const int slotw = ((sseg8 & 3) ^ fsw) * 8;          // u16
    const int krow = w * 8 + srow8;                     // K row (k-pos), 0..63
    const int d0 = w * 8 + srow8;                       // V d-row, 0..63 (+64)
    ushort* kdst = Ks + (sseg8 >> 2) * 2048 + krow * 32 + slotw;  // kr1: +4096
    ushort* vdst = Vs + (sseg8 >> 2) * 4096 + d0 * 32 + slotw;    // vr1: +2048
    const ushort* ksrc = K + ((size_t)(b * NKV_ + kvh) * S_ + krow) * HD_
                           + sseg8 * 8;
    const ushort* vsrc = V + ((size_t)(b * NKV_ + kvh) * HD_ + d0) * S_
                           + sseg8 * 8;
    const int rslot = (quad ^ ((lx >> 1) & 3)) * 8;     // read slot (u16)

    const ushort* qb_ = Q + ((size_t)(b * NH_ + h) * S_ + q0) * HD_;
    bf16x8 aq[4];
#pragma unroll
    for (int ks = 0; ks < 4; ++ks)
        aq[ks] = *(const bf16x8*)(qb_ + (size_t)(w * 16 + lx) * HD_ + ks * 32 + quad * 8);

    f32x4 o[8];
#pragma unroll
    for (int j = 0; j < 8; ++j) o[j] = (f32x4){0.f, 0.f, 0.f, 0.f};
    float mrow[4] = {-INFINITY, -INFINITY, -INFINITY, -INFINITY};
    float lp[4] = {0.f, 0.f, 0.f, 0.f};

    uint4 kr0, kr1, vr0, vr1;
    {
        const size_t kf = (size_t)tk0 * 64;
        kr0 = *(const uint4*)(ksrc + kf * HD_);
        kr1 = *(const uint4*)(ksrc + kf * HD_ + 64);
        vr0 = *(const uint4*)(vsrc + kf);
        vr1 = *(const uint4*)(vsrc + (size_t)64 * S_ + kf);
    }

    for (int tk = tk0; tk < tk1; ++tk) {
        const int k0 = tk * 64;
        asm volatile("s_barrier" ::: "memory");
        *(uint4*)(kdst +    0) = kr0;
        *(uint4*)(kdst + 4096) = kr1;
        *(uint4*)(vdst +    0) = vr0;
        *(uint4*)(vdst + 2048) = vr1;
        asm volatile("s_waitcnt lgkmcnt(0)" ::: "memory");
        asm volatile("s_barrier" ::: "memory");

        if (tk + 1 < tk1) {
            const size_t kf = (size_t)(k0 + 64);
            kr0 = *(const uint4*)(ksrc + kf * HD_);
            kr1 = *(const uint4*)(ksrc + kf * HD_ + 64);
            vr0 = *(const uint4*)(vsrc + kf);
            vr1 = *(const uint4*)(vsrc + (size_t)64 * S_ + kf);
        }

        f32x4 s[4];
#pragma unroll
        for (int j = 0; j < 4; ++j) s[j] = (f32x4){0.f, 0.f, 0.f, 0.f};
        __builtin_amdgcn_s_setprio(1);
#pragma unroll
        for (int ks = 0; ks < 4; ++ks) {
#pragma unroll
            for (int j = 0; j < 4; ++j) {
                bf16x8 bk = *(const bf16x8*)(Ks + ks * 2048 + (j * 16 + lx) * 32 + rslot);
                s[j] = __builtin_amdgcn_mfma_f32_16x16x32_bf16(aq[ks], bk, s[j], 0, 0, 0);
            }
        }
        __builtin_amdgcn_s_setprio(0);

        // causal mask: wave-uniform trigger (covers diag + fully-masked tiles)
        const int qrow_base = q0 + w * 16 + quad * 4;
        if (k0 + 63 > q0 + w * 16) {
#pragma unroll
            for (int reg = 0; reg < 4; ++reg) {
                const int qrow = qrow_base + reg;
#pragma unroll
                for (int j = 0; j < 4; ++j)
                    if (k0 + lx + 16 * j > qrow) s[j][reg] = -INFINITY;
            }
        }

        float rmx[4];
        bool need = false;
#pragma unroll
        for (int reg = 0; reg < 4; ++reg) {
            rmx[reg] = fmaxf(fmaxf(s[0][reg], s[1][reg]),
                             fmaxf(s[2][reg], s[3][reg]));
            need |= (rmx[reg] > mrow[reg] + 8.0f);
        }
        if (__any(need)) {
#pragma unroll
            for (int reg = 0; reg < 4; ++reg) {
                float rm = rmx[reg];
#pragma unroll
                for (int off = 1; off < 16; off <<= 1)
                    rm = fmaxf(rm, __shfl_xor(rm, off));
                const float mn = fmaxf(mrow[reg], rm);
                const float alpha = __expf(mrow[reg] - mn);
                mrow[reg] = mn;
                lp[reg] *= alpha;
#pragma unroll
                for (int j = 0; j < 8; ++j) o[j][reg] *= alpha;
            }
        }
#pragma unroll
        for (int reg = 0; reg < 4; ++reg) {
#pragma unroll
            for (int j = 0; j < 4; ++j) {
                const float p = __expf(s[j][reg] - mrow[reg]);
                lp[reg] += p;
                Ps[w * 1152 + (quad * 4 + reg) * 72 + lx + 16 * j] = f2bf(p);
            }
        }

        bf16x8 ap[2];
#pragma unroll
        for (int ks2 = 0; ks2 < 2; ++ks2)
            ap[ks2] = *(const bf16x8*)(Ps + w * 1152 + lx * 72 + ks2 * 32 + quad * 8);
        __builtin_amdgcn_s_setprio(1);
#pragma unroll
        for (int jd = 0; jd < 8; ++jd) {
#pragma unroll
            for (int ks2 = 0; ks2 < 2; ++ks2) {
                bf16x8 bv = *(const bf16x8*)(Vs + ks2 * 4096 + (jd * 16 + lx) * 32 + rslot);
                o[jd] = __builtin_amdgcn_mfma_f32_16x16x32_bf16(ap[ks2], bv, o[jd], 0, 0, 0);
            }
        }
        __builtin_amdgcn_s_setprio(0);
    }

    // ---- epilogue ----
#pragma unroll
    for (int reg = 0; reg < 4; ++reg) {
        float l = lp[reg];
#pragma unroll
        for (int off = 1; off < 16; off <<= 1) l += __shfl_xor(l, off);
        lp[reg] = l;
    }
    if (!split) {
#pragma unroll
        for (int reg = 0; reg < 4; ++reg) {
            const float inv = 1.0f / lp[reg];
            const size_t yb = (size_t)(b * S_ + q0 + w * 16 + quad * 4 + reg) * (NH_ * HD_)
                            + h * HD_ + lx;
#pragma unroll
            for (int jd = 0; jd < 8; ++jd)
                Y[yb + jd * 16] = f2bf(o[jd][reg] * inv);
        }
    } else {
        const int sp = ((b * NH_ + h) * 11 + (qb - 5)) * 2 + halfsel;
        float* mlb = ML + (size_t)sp * 256;
#pragma unroll
        for (int reg = 0; reg < 4; ++reg) {
            const int row = w * 16 + quad * 4 + reg;   // 0..127
            if (lx == 0) {
                mlb[row] = mrow[reg];
                mlb[128 + row] = lp[reg];
            }
            float* ob = OP + ((size_t)sp * 128 + row) * 128 + lx;
#pragma unroll
            for (int jd = 0; jd < 8; ++jd)
                ob[jd * 16] = o[jd][reg];
        }
    }
}

// ------------- K3b: merge the two KV-halves of heavy q-blocks -------------
__global__ __launch_bounds__(256) void attn_combine(
    const float* __restrict__ OP, const float* __restrict__ ML,
    ushort* __restrict__ Y)
{
    const int gx = blockIdx.x, h = blockIdx.y, b = blockIdx.z;
    const int qb = 5 + gx;
    const int q0 = qb * 128;
    const int sp0 = ((b * NH_ + h) * 11 + gx) * 2;
    const float* ml0 = ML + (size_t)sp0 * 256;
    const float* ml1 = ML + (size_t)(sp0 + 1) * 256;
    const float* o0 = OP + (size_t)sp0 * 128 * 128;
    const float* o1 = OP + (size_t)(sp0 + 1) * 128 * 128;
    const int d = threadIdx.x & 127, rg = threadIdx.x >> 7;
#pragma unroll
    for (int r = rg; r < 128; r += 2) {
        const float m0 = ml0[r], l0 = ml0[128 + r];
        const float m1 = ml1[r], l1 = ml1[128 + r];
        const float m = fmaxf(m0, m1);
        const float w0 = __expf(m0 - m), w1 = __expf(m1 - m);
        const float inv = 1.0f / (l0 * w0 + l1 * w1);
        const float v = (o0[r * 128 + d] * w0 + o1[r * 128 + d] * w1) * inv;
        Y[((size_t)(b * S_ + q0 + r)) * (NH_ * HD_) + h * HD_ + d] = f2bf(v);
    }
}

extern "C" void kernel_launch(void* const* d_in, const int* in_sizes, int n_in,
                              void* d_out, int out_size, void* d_ws, size_t ws_size,
                              hipStream_t stream)
{
    const float* x     = (const float*)d_in[0];
    const float* freqs = (const float*)d_in[1];
    const float* wqkv  = (const float*)d_in[2];
    const float* wo    = (const float*)d_in[3];
    const float* qw    = (const float*)d_in[4];
    const float* kw    = (const float*)d_in[5];
    float* out = (float*)d_out;

    // ws layout v14 (== v12):
    //   [0..16.78M)       qbf   (B,NH,S,HD) bf16
    //   [16.78M..20.97M)  kbf   (B,NKV,S,HD) bf16
    //   [20.97M..25.17M)  vtb   (B,NKV,HD,S) bf16 transposed
    //   [25.17M..41.94M)  ybf   (B,S,NH*HD) bf16
    //   [41.94M..50.33M)  wobf
    //   [50.33M..100.66M) dead after K1 (wqkvbf, xbf) -> attn partials:
    //     OP: 704 sp x 128 x 128 f32 = 46.14M  @ 50331648
    //     ML: 704 sp x 256 f32      = 0.72M    @ 96468992
    char* ws = (char*)d_ws;
    ushort* qbf    = (ushort*)(ws + 0);
    ushort* kbf    = (ushort*)(ws + 16777216);
    ushort* vtb    = (ushort*)(ws + 20971520);
    ushort* ybf    = (ushort*)(ws + 25165824);
    ushort* wobf   = (ushort*)(ws + 41943040);
    ushort* wqkvbf = (ushort*)(ws + 50331648);
    ushort* xbf    = (ushort*)(ws + 83886080);
    float*  OP     = (float*)(ws + 50331648);
    float*  ML     = (float*)(ws + 96468992);

    // single pack launch: x + wqkv + wo (all independent of K1..K4)
    pack_all<<<(NP_X + NP_W + NP_O + 255) / 256, 256, 0, stream>>>(
        x, wqkv, wo, xbf, wqkvbf, wobf);
    // K1 fused: qkv GEMM + rmsnorm + rope + scale + bf16 + V^T (BK=32)
    gemm_qkv_fused<<<dim3(EQKV_ / 128, M_ / 128), 256, 0, stream>>>(
        xbf, wqkvbf, freqs, qw, kw, qbf, kbf, vtb, D_);
    // K3: 128-row Q-blocks, 8 waves; KV-split for qb>=5 -> ybf / partials
    flash_attn_mfma<<<dim3(27, NH_, B_), 512, 0, stream>>>(qbf, kbf, vtb, ybf,
                                                           OP, ML);
    // K3b: merge heavy-block halves -> ybf rows 640..2047 per (b,h)
    attn_combine<<<dim3(11, NH_, B_), 256, 0, stream>>>(OP, ML, ybf);
    // K4: out = y @ wo^T  (bf16 MFMA, BK=64)
    gemm_nt_bf16<<<dim3(D_ / 128, M_ / 128), 256, 0, stream>>>(
        ybf, wobf, out, M_, D_, NH_ * HD_);
}